// Round 5
// baseline (333.120 us; speedup 1.0000x reference)
//
#include <hip/hip_runtime.h>
#include <math.h>

#define NN 8192
#define MM 64
#define BB 128
#define HIDC 512
#define OUTC 256
#define SEQW 63

// per-WG local rows: 4096 own + 2 halo each side, padded to 4160 (65 groups of 64)
#define LROWS 4160
#define OWN_LO 2
#define OWN_HI 4098

// ws layout: int flags[256] at the front; float data at FBASE + b*BSTRIDE
//   +0:   msumP h0[64]   +64:  msumP h1[64]
//   +128: outP  h0[64]   +192: outP  h1[64]
//   +256: scalars {0+h psumW, 2+h psumR, 4+h esum0, 6+h wpsum0, 8+h esum1, 10+h wpsum1, 12+h swr}
#define FBASE 256
#define BSTRIDE 320

__device__ __forceinline__ float lrelu(float x){ return x > 0.f ? x : 0.01f*x; }
__device__ __forceinline__ float sigm(float x){ return 1.f/(1.f+__expf(-x)); }

__device__ float block_reduce_sum(float v, float* red) {
  for (int m = 32; m >= 1; m >>= 1) v += __shfl_xor(v, m);
  int wid = threadIdx.x >> 6;
  if ((threadIdx.x & 63) == 0) red[wid] = v;
  __syncthreads();
  if (threadIdx.x == 0) { float s = 0.f; for (int i = 0; i < 16; ++i) s += red[i]; red[0] = s; }
  __syncthreads();
  float r = red[0];
  __syncthreads();
  return r;
}

// pairwise barrier between blocks 2b and 2b+1; k strictly increasing per launch; flags zeroed by init kernel
__device__ __forceinline__ void pair_sync(int* flags, int me, int k) {
  __syncthreads();
  if (threadIdx.x == 0) {
    __threadfence();  // release prior global writes (device scope, invalidates/writes through L1)
    __hip_atomic_store(&flags[me], k, __ATOMIC_RELEASE, __HIP_MEMORY_SCOPE_AGENT);
    while (__hip_atomic_load(&flags[me ^ 1], __ATOMIC_ACQUIRE, __HIP_MEMORY_SCOPE_AGENT) < k) {}
    __threadfence();  // acquire partner's writes; buffer_inv covers this CU's L1 for all waves
  }
  __syncthreads();
}

__global__ void ntm_init(int* flags) { flags[threadIdx.x] = 0; }

__global__ __launch_bounds__(1024, 1) void ntm_fused2(
    const float* __restrict__ x,    const float* __restrict__ bank,
    const float* __restrict__ wrp,  const float* __restrict__ wwp,
    const float* __restrict__ W0,   const float* __restrict__ b0,
    const float* __restrict__ W1,   const float* __restrict__ b1,
    const float* __restrict__ Wc,   const float* __restrict__ bc,
    const float* __restrict__ Wr,   const float* __restrict__ br,
    const float* __restrict__ Ww,   const float* __restrict__ bw,
    const float* __restrict__ Wea,  const float* __restrict__ bea,
    const float* __restrict__ Wsp,  const float* __restrict__ bsp,
    const float* __restrict__ Wo,   const float* __restrict__ bo,
    float* __restrict__ out, float* __restrict__ wsf, int* __restrict__ flags)
{
  const int blk = blockIdx.x;
  const int b = blk >> 1;
  const int h = blk & 1;
  const int t = threadIdx.x;
  const int start = h * 4096;
  const int cg = t & 15;          // 16 lanes per row (4 floats each)
  const int rl = t >> 4;          // 0..63 rows per group
  const float* bank_b = bank + (size_t)b * NN * MM;
  const size_t bN = (size_t)b * NN;
  const int fb = FBASE + b * BSTRIDE;
  const int sb = fb + 256;

  __shared__ __align__(16) float A[LROWS];   // dotw -> exp/buf0 (addr0)
  __shared__ __align__(16) float Bb[LROWS];  // dotr -> adj dot -> exp/buf1 (addr1)
  __shared__ __align__(16) float C[LROWS];   // rn2  -> adj rn2 -> raw wr p (addr1 out)
  __shared__ __align__(16) float E[LROWS];   // ww (normalized)
  __shared__ float red[16];
  __shared__ __align__(16) float msum[64];
  __shared__ __align__(16) float dvec[64];
  __shared__ float prm[20];                  // 0..7 write params, 8..15 read params, 16 dd2, 17 dkr
  __shared__ __align__(16) float cat[128], eaS[128];
  __shared__ __align__(16) float h0[HIDC], h1[HIDC], ct[OUTC];
  __shared__ __align__(16) float rrr[72], rww[72];

  // ---------------- controller MLP (redundant on both blocks of the pair) ----------------
  if (t < 64) cat[t] = x[b*64 + t];
  __syncthreads();
  if (t < HIDC) {
    float acc = b0[t];
    #pragma unroll 4
    for (int i = 0; i < 64; ++i) acc += cat[i] * W0[i*HIDC + t];
    h0[t] = lrelu(acc);
  }
  __syncthreads();
  if (t < HIDC) {
    float acc = b1[t];
    for (int i = 0; i < HIDC; ++i) acc += h0[i] * W1[i*HIDC + t];
    h1[t] = lrelu(acc);
  }
  __syncthreads();
  if (t < OUTC) {
    float acc = bc[t];
    for (int i = 0; i < HIDC; ++i) acc += h1[i] * Wc[i*OUTC + t];
    ct[t] = lrelu(acc);
  }
  __syncthreads();
  if (t < 70) {
    float ar = br[t], aw = bw[t];
    for (int i = 0; i < OUTC; ++i) { float c = ct[i]; ar += c * Wr[i*70 + t]; aw += c * Ww[i*70 + t]; }
    rrr[t] = ar; rww[t] = aw;
  }
  __syncthreads();
  if (t < 2) {
    const float* rv = (t == 0) ? rww : rrr;  // t=0: write set, t=1: read set
    float* p = prm + t*8;
    p[0] = fmaxf(rv[64], 0.f) + 1e-8f;       // beta
    p[1] = 1.f/(1.f+expf(-rv[65]));          // g
    float m = fmaxf(rv[66], fmaxf(rv[67], rv[68]));
    float e0 = expf(rv[66]-m), e1 = expf(rv[67]-m), e2 = expf(rv[68]-m);
    float ss = e0+e1+e2;
    p[2] = e0/ss; p[3] = e1/ss; p[4] = e2/ss;
    p[5] = fmaxf(rv[69], 0.f) + 1.f;         // gamma
    float n2 = 0.f;
    for (int i = 0; i < 64; ++i) n2 += rv[i]*rv[i];
    p[6] = sqrtf(n2);                        // |k|
  }
  if (t < 64) msum[t] = 0.f;
  __syncthreads();

  // ---------------- w_prev partial sums (own half) ----------------
  {
    float sW = 0.f, sR = 0.f;
    for (int l = t; l < 4096; l += 1024) {
      int g = start + l;
      sW += wwp[bN + g];
      sR += wrp[bN + g];
    }
    float rW = block_reduce_sum(sW, red);
    float rR = block_reduce_sum(sR, red);
    if (t == 0) { wsf[sb + 0 + h] = rW; wsf[sb + 2 + h] = rR; }
  }

  // ---------------- pass1: dotw->A, dotr->Bb, rn2->C over l in [0,4160) ----------------
  {
    float4 kw4 = *(float4*)&rww[cg*4];
    float4 kr4 = *(float4*)&rrr[cg*4];
    float m0=0.f, m1=0.f, m2=0.f, m3=0.f;
    for (int sup = 0; sup < 8; ++sup) {
      float4 v[8];
      #pragma unroll
      for (int j = 0; j < 8; ++j) {
        int l = sup*512 + j*64 + rl;
        int g = (start + l - 2) & (NN-1);
        v[j] = *(const float4*)&bank_b[(size_t)g*MM + cg*4];
      }
      float dw[8], dr[8], r2[8];
      #pragma unroll
      for (int j = 0; j < 8; ++j) {
        dw[j] = v[j].x*kw4.x + v[j].y*kw4.y + v[j].z*kw4.z + v[j].w*kw4.w;
        dr[j] = v[j].x*kr4.x + v[j].y*kr4.y + v[j].z*kr4.z + v[j].w*kr4.w;
        r2[j] = v[j].x*v[j].x + v[j].y*v[j].y + v[j].z*v[j].z + v[j].w*v[j].w;
        int l = sup*512 + j*64 + rl;
        if (l >= OWN_LO && l < OWN_HI) { m0 += v[j].x; m1 += v[j].y; m2 += v[j].z; m3 += v[j].w; }
      }
      #pragma unroll
      for (int m = 1; m < 16; m <<= 1) {
        #pragma unroll
        for (int j = 0; j < 8; ++j) {
          dw[j] += __shfl_xor(dw[j], m);
          dr[j] += __shfl_xor(dr[j], m);
          r2[j] += __shfl_xor(r2[j], m);
        }
      }
      if (cg == 0) {
        #pragma unroll
        for (int j = 0; j < 8; ++j) {
          int l = sup*512 + j*64 + rl;
          A[l] = dw[j]; Bb[l] = dr[j]; C[l] = r2[j];
        }
      }
    }
    { // tail group l in [4096,4160)
      int l = 4096 + rl;
      int g = (start + l - 2) & (NN-1);
      float4 v = *(const float4*)&bank_b[(size_t)g*MM + cg*4];
      float dw = v.x*kw4.x + v.y*kw4.y + v.z*kw4.z + v.w*kw4.w;
      float dr = v.x*kr4.x + v.y*kr4.y + v.z*kr4.z + v.w*kr4.w;
      float r2 = v.x*v.x + v.y*v.y + v.z*v.z + v.w*v.w;
      if (l < OWN_HI) { m0 += v.x; m1 += v.y; m2 += v.z; m3 += v.w; }
      for (int m = 1; m < 16; m <<= 1) {
        dw += __shfl_xor(dw, m); dr += __shfl_xor(dr, m); r2 += __shfl_xor(r2, m);
      }
      if (cg == 0) { A[l] = dw; Bb[l] = dr; C[l] = r2; }
    }
    atomicAdd(&msum[cg*4+0], m0);
    atomicAdd(&msum[cg*4+1], m1);
    atomicAdd(&msum[cg*4+2], m2);
    atomicAdd(&msum[cg*4+3], m3);
    __syncthreads();
    if (t < 64) wsf[fb + h*64 + t] = msum[t];
  }
  pair_sync(flags, blk, 1);

  // ---------------- ea (redundant on both): d, dd2, dkr ----------------
  if (t < 64) {
    float s = wsf[fb + t] + wsf[fb + 64 + t];
    cat[t] = s * (1.0f/NN);
  } else if (t < 128) {
    cat[t] = rww[t-64];
  }
  __syncthreads();
  if (t < 128) {
    float acc = bea[t];
    for (int i = 0; i < 128; ++i) acc += cat[i] * Wea[i*128 + t];
    eaS[t] = acc;
  }
  __syncthreads();
  if (t < 64) dvec[t] = eaS[64+t] - sigm(eaS[t]);
  __syncthreads();
  if (t == 0) {
    float dd = 0.f, dk = 0.f;
    for (int i = 0; i < 64; ++i) { float dv = dvec[i]; dd += dv*dv; dk += dv*rrr[i]; }
    prm[16] = dd; prm[17] = dk;
  }
  __syncthreads();

  // ---------------- addr0 (write addressing): A,C -> ww into E ----------------
  {
    float beta = prm[0], g = prm[1], s0 = prm[2], s1 = prm[3], s2 = prm[4], gam = prm[5], kn = prm[6];
    float psum = wsf[sb+0] + wsf[sb+1];
    float lsum = 0.f;
    for (int l = t; l < 4100; l += 1024) {
      float c = A[l] / fmaxf(sqrtf(C[l]) * kn, 1e-8f);
      float e = __expf(beta * (c - 1.f));    // z - beta bound (shift-invariant softmax)
      A[l] = e;
      if (l >= OWN_LO && l < OWN_HI) lsum += e;
    }
    float r = block_reduce_sum(lsum, red);
    if (t == 0) wsf[sb+4+h] = r;
    pair_sync(flags, blk, 2);
    float esum = wsf[sb+4] + wsf[sb+5];
    float ie = g/esum, ip = (1.f-g)/psum;
    for (int l = t; l < 4100; l += 1024) {
      int gg = (start + l - 2) & (NN-1);
      A[l] = A[l]*ie + wwp[bN + gg]*ip;
    }
    __syncthreads();
    float l2 = 0.f;
    for (int l = t + 1; l < 4099; l += 1024) {
      float wsv = s0*A[l-1] + s1*A[l] + s2*A[l+1];
      float p = exp2f(gam * log2f(wsv));
      E[l] = p;
      if (l >= OWN_LO && l < OWN_HI) l2 += p;
    }
    r = block_reduce_sum(l2, red);
    if (t == 0) wsf[sb+6+h] = r;
    pair_sync(flags, blk, 3);
    float invp = 1.f/(wsf[sb+6] + wsf[sb+7]);
    for (int l = t + 1; l < 4099; l += 1024) E[l] *= invp;
  }
  __syncthreads();

  // ---------------- pass2: dotd; adjust Bb (dot) and C (rn2) in place ----------------
  {
    float4 d4 = *(float4*)&dvec[cg*4];
    float dd2 = prm[16], dkr = prm[17];
    for (int sup = 0; sup < 8; ++sup) {
      float4 v[8];
      #pragma unroll
      for (int j = 0; j < 8; ++j) {
        int l = sup*512 + j*64 + rl;
        int g = (start + l - 2) & (NN-1);
        v[j] = *(const float4*)&bank_b[(size_t)g*MM + cg*4];
      }
      float dd[8];
      #pragma unroll
      for (int j = 0; j < 8; ++j)
        dd[j] = v[j].x*d4.x + v[j].y*d4.y + v[j].z*d4.z + v[j].w*d4.w;
      #pragma unroll
      for (int m = 1; m < 16; m <<= 1) {
        #pragma unroll
        for (int j = 0; j < 8; ++j) dd[j] += __shfl_xor(dd[j], m);
      }
      if (cg == 0) {
        #pragma unroll
        for (int j = 0; j < 8; ++j) {
          int l = sup*512 + j*64 + rl;
          if (l >= 1 && l < 4099) {
            float wwv = E[l];
            Bb[l] += wwv * dkr;
            C[l]  = fmaxf(C[l] + 2.f*wwv*dd[j] + wwv*wwv*dd2, 0.f);
          }
        }
      }
    }
    { // tail
      int l = 4096 + rl;
      int g = (start + l - 2) & (NN-1);
      float4 v = *(const float4*)&bank_b[(size_t)g*MM + cg*4];
      float dd = v.x*d4.x + v.y*d4.y + v.z*d4.z + v.w*d4.w;
      for (int m = 1; m < 16; m <<= 1) dd += __shfl_xor(dd, m);
      if (cg == 0 && l < 4099) {
        float wwv = E[l];
        Bb[l] += wwv * dkr;
        C[l]  = fmaxf(C[l] + 2.f*wwv*dd + wwv*wwv*dd2, 0.f);
      }
    }
  }
  __syncthreads();

  // ---------------- addr1 (read addressing): Bb,C -> raw p into C; swr partial ----------------
  {
    float beta = prm[8], g = prm[9], s0 = prm[10], s1 = prm[11], s2 = prm[12], gam = prm[13], kn = prm[14];
    float psum = wsf[sb+2] + wsf[sb+3];
    float lsum = 0.f;
    for (int l = t; l < 4100; l += 1024) {
      float c = Bb[l] / fmaxf(sqrtf(C[l]) * kn, 1e-8f);
      float e = __expf(beta * (c - 1.f));
      Bb[l] = e;
      if (l >= OWN_LO && l < OWN_HI) lsum += e;
    }
    float r = block_reduce_sum(lsum, red);
    if (t == 0) wsf[sb+8+h] = r;
    pair_sync(flags, blk, 4);
    float esum = wsf[sb+8] + wsf[sb+9];
    float ie = g/esum, ip = (1.f-g)/psum;
    for (int l = t; l < 4100; l += 1024) {
      int gg = (start + l - 2) & (NN-1);
      Bb[l] = Bb[l]*ie + wrp[bN + gg]*ip;
    }
    __syncthreads();
    float l2 = 0.f, lswr = 0.f;
    for (int l = t + 1; l < 4099; l += 1024) {
      float wsv = s0*Bb[l-1] + s1*Bb[l] + s2*Bb[l+1];
      float p = exp2f(gam * log2f(wsv));
      C[l] = p;                               // raw (unnormalized) read weight
      if (l >= OWN_LO && l < OWN_HI) { l2 += p; lswr += p * E[l]; }
    }
    r = block_reduce_sum(l2, red);
    if (t == 0) wsf[sb+10+h] = r;
    r = block_reduce_sum(lswr, red);
    if (t == 0) wsf[sb+12+h] = r;
    // no sync needed yet: pass3 uses only local C/bank
  }
  if (t < 64) msum[t] = 0.f;
  __syncthreads();

  // ---------------- pass3: outP = sum_own p[l] * bank[row,:] ----------------
  {
    float a0=0.f, a1=0.f, a2=0.f, a3=0.f;
    for (int sup = 0; sup < 8; ++sup) {
      float4 v[8]; float wv[8];
      #pragma unroll
      for (int j = 0; j < 8; ++j) {
        int l = sup*512 + j*64 + rl;
        int g = (start + l - 2) & (NN-1);
        v[j] = *(const float4*)&bank_b[(size_t)g*MM + cg*4];
        wv[j] = C[l];
      }
      #pragma unroll
      for (int j = 0; j < 8; ++j) {
        int l = sup*512 + j*64 + rl;
        if (l >= OWN_LO && l < OWN_HI) {
          a0 += wv[j]*v[j].x; a1 += wv[j]*v[j].y;
          a2 += wv[j]*v[j].z; a3 += wv[j]*v[j].w;
        }
      }
    }
    { // tail
      int l = 4096 + rl;
      int g = (start + l - 2) & (NN-1);
      float4 v = *(const float4*)&bank_b[(size_t)g*MM + cg*4];
      float wv = C[l];
      if (l < OWN_HI) { a0 += wv*v.x; a1 += wv*v.y; a2 += wv*v.z; a3 += wv*v.w; }
    }
    atomicAdd(&msum[cg*4+0], a0);
    atomicAdd(&msum[cg*4+1], a1);
    atomicAdd(&msum[cg*4+2], a2);
    atomicAdd(&msum[cg*4+3], a3);
  }
  __syncthreads();
  if (t < 64) wsf[fb + 128 + h*64 + t] = msum[t];
  pair_sync(flags, blk, 5);

  // ---------------- final head (block h==0 of each pair) ----------------
  if (h == 0) {
    float wp1 = wsf[sb+10] + wsf[sb+11];
    float sw  = wsf[sb+12] + wsf[sb+13];
    float iv  = 1.f / wp1;
    if (t < 64) cat[t] = (wsf[fb+128+t] + wsf[fb+192+t] + sw*dvec[t]) * iv;
    __syncthreads();
    if (t < HIDC) {
      float acc = bsp[t];
      #pragma unroll 4
      for (int i = 0; i < 64; ++i) acc += cat[i] * Wsp[i*HIDC + t];
      h0[t] = lrelu(acc);
    }
    __syncthreads();
    if (t < SEQW) {
      float a = bo[t];
      for (int i = 0; i < HIDC; ++i) a += h0[i] * Wo[i*SEQW + t];
      out[b*SEQW + t] = sigm(a);
    }
  }
}

extern "C" void kernel_launch(void* const* d_in, const int* in_sizes, int n_in,
                              void* d_out, int out_size, void* d_ws, size_t ws_size,
                              hipStream_t stream) {
  const float* x    = (const float*)d_in[0];
  const float* bank = (const float*)d_in[1];
  const float* wrp  = (const float*)d_in[2];
  const float* wwp  = (const float*)d_in[3];
  const float* W0   = (const float*)d_in[4];
  const float* b0   = (const float*)d_in[5];
  const float* W1   = (const float*)d_in[6];
  const float* b1   = (const float*)d_in[7];
  const float* Wc   = (const float*)d_in[8];
  const float* bc   = (const float*)d_in[9];
  const float* Wr   = (const float*)d_in[10];
  const float* br   = (const float*)d_in[11];
  const float* Ww   = (const float*)d_in[12];
  const float* bw   = (const float*)d_in[13];
  const float* Wea  = (const float*)d_in[14];
  const float* bea  = (const float*)d_in[15];
  const float* Wsp  = (const float*)d_in[16];
  const float* bsp  = (const float*)d_in[17];
  const float* Wo   = (const float*)d_in[18];
  const float* bo   = (const float*)d_in[19];
  float* out = (float*)d_out;
  int*   flags = (int*)d_ws;
  float* wsf   = (float*)d_ws;

  ntm_init<<<1, 256, 0, stream>>>(flags);
  ntm_fused2<<<2*BB, 1024, 0, stream>>>(x, bank, wrp, wwp,
                                        W0,b0, W1,b1, Wc,bc, Wr,br, Ww,bw,
                                        Wea,bea, Wsp,bsp, Wo,bo, out, wsf, flags);
}

// Round 6
// 325.692 us; speedup vs baseline: 1.0228x; 1.0228x over previous
//
#include <hip/hip_runtime.h>
#include <math.h>

#define NN 8192
#define MM 64
#define BB 128
#define HIDC 512
#define OUTC 256
#define SEQW 63

#define CHUNKS 64        // row-chunks per batch (128 rows each) for bank passes
#define CB 64            // batches per batch-chunk (bank slice = 134 MB < L3)

// ---- workspace layout (float offsets) ----
#define OFF_KR    0
#define OFF_KW    8192
#define OFF_PR    16384
#define OFF_PW    17408
#define OFF_BS    18432                    // per-b 8: [2]=dd2 [3]=dkr [4]=swr
#define OFF_D     19456
#define OFF_PMSUM 27648                    // B*CHUNKS*64
#define OFF_POUT  (27648 + 524288)
#define OFF_DOTW  (27648 + 2*524288)
#define OFF_DOTR  (27648 + 2*524288 + 1048576)
#define OFF_RN2   (27648 + 2*524288 + 2*1048576)
#define OFF_DOTD  (27648 + 2*524288 + 3*1048576)
#define OFF_WW    (27648 + 2*524288 + 4*1048576)
#define OFF_WR    (27648 + 2*524288 + 5*1048576)

__device__ __forceinline__ float lrelu(float x){ return x > 0.f ? x : 0.01f*x; }
__device__ __forceinline__ float sigm(float x){ return 1.f/(1.f+__expf(-x)); }

__device__ float block_reduce_sum(float v, float* red) {
  for (int m = 32; m >= 1; m >>= 1) v += __shfl_xor(v, m);
  int wid = threadIdx.x >> 6;
  int nw = (blockDim.x + 63) >> 6;
  if ((threadIdx.x & 63) == 0) red[wid] = v;
  __syncthreads();
  if (threadIdx.x == 0) { float s = 0.f; for (int i = 0; i < nw; ++i) s += red[i]; red[0] = s; }
  __syncthreads();
  float r = red[0];
  __syncthreads();
  return r;
}

// ---------------- controller MLP (all batches) ----------------
__global__ __launch_bounds__(512) void ctrl_kernel(
    const float* __restrict__ x,
    const float* __restrict__ W0, const float* __restrict__ b0,
    const float* __restrict__ W1, const float* __restrict__ b1,
    const float* __restrict__ Wc, const float* __restrict__ bc,
    const float* __restrict__ Wr, const float* __restrict__ br,
    const float* __restrict__ Ww, const float* __restrict__ bw,
    float* __restrict__ ws)
{
  int b = blockIdx.x, t = threadIdx.x;
  __shared__ float xs[64];
  __shared__ float h0[512];
  __shared__ float h1[512];
  __shared__ float ct[256];
  __shared__ float rr[70], rw[70];
  if (t < 64) xs[t] = x[b*64 + t];
  __syncthreads();
  float acc = b0[t];
  for (int i = 0; i < 64; ++i) acc += xs[i] * W0[i*HIDC + t];
  h0[t] = lrelu(acc);
  __syncthreads();
  acc = b1[t];
  for (int i = 0; i < 512; ++i) acc += h0[i] * W1[i*HIDC + t];
  h1[t] = lrelu(acc);
  __syncthreads();
  if (t < 256) {
    acc = bc[t];
    for (int i = 0; i < 512; ++i) acc += h1[i] * Wc[i*OUTC + t];
    ct[t] = lrelu(acc);
  }
  __syncthreads();
  if (t < 70) {
    float ar = br[t], aw = bw[t];
    for (int i = 0; i < 256; ++i) { float c = ct[i]; ar += c * Wr[i*70 + t]; aw += c * Ww[i*70 + t]; }
    rr[t] = ar; rw[t] = aw;
  }
  __syncthreads();
  if (t < 64) { ws[OFF_KR + b*64 + t] = rr[t]; ws[OFF_KW + b*64 + t] = rw[t]; }
  if (t == 0) {
    float* p = ws + OFF_PR + b*8;
    p[0] = fmaxf(rr[64], 0.f) + 1e-8f;
    p[1] = sigm(rr[65]);
    float m = fmaxf(rr[66], fmaxf(rr[67], rr[68]));
    float e0 = expf(rr[66]-m), e1 = expf(rr[67]-m), e2 = expf(rr[68]-m);
    float ss = e0+e1+e2;
    p[2] = e0/ss; p[3] = e1/ss; p[4] = e2/ss;
    p[5] = fmaxf(rr[69], 0.f) + 1.f;
    float n2 = 0.f; for (int i = 0; i < 64; ++i) n2 += rr[i]*rr[i];
    p[6] = sqrtf(n2);
  }
  if (t == 1) {
    float* p = ws + OFF_PW + b*8;
    p[0] = fmaxf(rw[64], 0.f) + 1e-8f;
    p[1] = sigm(rw[65]);
    float m = fmaxf(rw[66], fmaxf(rw[67], rw[68]));
    float e0 = expf(rw[66]-m), e1 = expf(rw[67]-m), e2 = expf(rw[68]-m);
    float ss = e0+e1+e2;
    p[2] = e0/ss; p[3] = e1/ss; p[4] = e2/ss;
    p[5] = fmaxf(rw[69], 0.f) + 1.f;
    float n2 = 0.f; for (int i = 0; i < 64; ++i) n2 += rw[i]*rw[i];
    p[6] = sqrtf(n2);
  }
}

// ---------------- pass 1 (chunk of CB batches) ----------------
__global__ __launch_bounds__(256, 4) void bank_pass1(const float* __restrict__ bank, float* __restrict__ ws, int bbase)
{
  int gb = blockIdx.x;
  int b  = bbase + (gb >> 6);
  int ch = gb & 63;
  int n0 = ch << 7;               // 128 rows per block
  int t = threadIdx.x;
  int cg = t & 15;
  int rl = t >> 4;
  __shared__ float kwS[64], krS[64], msum[64];
  if (t < 64) { kwS[t] = ws[OFF_KW + b*64 + t]; krS[t] = ws[OFF_KR + b*64 + t]; msum[t] = 0.f; }
  __syncthreads();
  float4 kw4 = *(float4*)&kwS[cg*4];
  float4 kr4 = *(float4*)&krS[cg*4];

  float4 v[8];
  #pragma unroll
  for (int it = 0; it < 8; ++it) {
    int n = n0 + rl + it*16;
    v[it] = *(const float4*)&bank[((size_t)b*NN + n)*MM + cg*4];
  }
  float dw[8], dr[8], r2[8];
  float m0=0.f, m1=0.f, m2=0.f, m3=0.f;
  #pragma unroll
  for (int it = 0; it < 8; ++it) {
    dw[it] = v[it].x*kw4.x + v[it].y*kw4.y + v[it].z*kw4.z + v[it].w*kw4.w;
    dr[it] = v[it].x*kr4.x + v[it].y*kr4.y + v[it].z*kr4.z + v[it].w*kr4.w;
    r2[it] = v[it].x*v[it].x + v[it].y*v[it].y + v[it].z*v[it].z + v[it].w*v[it].w;
    m0 += v[it].x; m1 += v[it].y; m2 += v[it].z; m3 += v[it].w;
  }
  #pragma unroll
  for (int m = 1; m < 16; m <<= 1) {
    #pragma unroll
    for (int it = 0; it < 8; ++it) {
      dw[it] += __shfl_xor(dw[it], m);
      dr[it] += __shfl_xor(dr[it], m);
      r2[it] += __shfl_xor(r2[it], m);
    }
  }
  if (cg == 0) {
    size_t base = (size_t)b*NN + n0 + rl;
    #pragma unroll
    for (int it = 0; it < 8; ++it) {
      ws[OFF_DOTW + base + it*16] = dw[it];
      ws[OFF_DOTR + base + it*16] = dr[it];
      ws[OFF_RN2  + base + it*16] = r2[it];
    }
  }
  atomicAdd(&msum[cg*4+0], m0);
  atomicAdd(&msum[cg*4+1], m1);
  atomicAdd(&msum[cg*4+2], m2);
  atomicAdd(&msum[cg*4+3], m3);
  __syncthreads();
  if (t < 64) ws[OFF_PMSUM + (size_t)(b*CHUNKS + ch)*64 + t] = msum[t];
}

// ---------------- addr0: ea prefix + write addressing (chunk of CB batches) ----------------
__global__ __launch_bounds__(1024, 1) void address0(
    const float* __restrict__ wprev,
    const float* __restrict__ Wea, const float* __restrict__ bea,
    float* __restrict__ ws, int bbase)
{
  int b = bbase + blockIdx.x, t = threadIdx.x;
  __shared__ float buf[NN];
  __shared__ float red[16];
  __shared__ float cat[128], eaS[128], dS[64];

  float wpr[8];
  float lps = 0.f;
  #pragma unroll
  for (int i = 0; i < 8; ++i) {
    wpr[i] = wprev[(size_t)b*NN + t + i*1024];
    lps += wpr[i];
  }
  float psum = block_reduce_sum(lps, red);

  // ea prefix
  if (t < 64) {
    float s = 0.f;
    for (int ch = 0; ch < CHUNKS; ++ch) s += ws[OFF_PMSUM + ((size_t)b*CHUNKS + ch)*64 + t];
    cat[t] = s * (1.0f/NN);
  } else if (t < 128) {
    cat[t] = ws[OFF_KW + b*64 + (t-64)];
  }
  __syncthreads();
  if (t < 128) {
    float acc = bea[t];
    for (int i = 0; i < 128; ++i) acc += cat[i] * Wea[i*128 + t];
    eaS[t] = acc;
  }
  __syncthreads();
  if (t < 64) {
    float dv = eaS[64+t] - sigm(eaS[t]);
    dS[t] = dv;
    ws[OFF_D + b*64 + t] = dv;
  }
  __syncthreads();
  if (t == 0) {
    float dd = 0.f, dk = 0.f;
    for (int i = 0; i < 64; ++i) { float dv = dS[i]; dd += dv*dv; dk += dv * ws[OFF_KR + b*64 + i]; }
    ws[OFF_BS + b*8 + 2] = dd;
    ws[OFF_BS + b*8 + 3] = dk;
  }
  __syncthreads();

  const float* prm = ws + OFF_PW + b*8;
  float beta = prm[0], g = prm[1], s0 = prm[2], s1 = prm[3], s2 = prm[4], gamma = prm[5], knorm = prm[6];

  float lsum = 0.f;
  #pragma unroll
  for (int i = 0; i < 8; ++i) {
    int n = t + i*1024;
    size_t o = (size_t)b*NN + n;
    float c = ws[OFF_DOTW + o] / fmaxf(sqrtf(ws[OFF_RN2 + o]) * knorm, 1e-8f);
    float e = __expf(beta * (c - 1.f));   // exact shift: cos <= 1
    buf[n] = e;
    lsum += e;
  }
  float esum = block_reduce_sum(lsum, red);
  float ie = g/esum, ip = (1.f-g)/psum;
  #pragma unroll
  for (int i = 0; i < 8; ++i) {
    int n = t + i*1024;
    buf[n] = buf[n]*ie + wpr[i]*ip;
  }
  __syncthreads();
  float l2 = 0.f;
  float wpv[8];
  #pragma unroll
  for (int i = 0; i < 8; ++i) {
    int n = t + i*1024;
    float wsv = s0*buf[(n + NN - 1) & (NN-1)] + s1*buf[n] + s2*buf[(n + 1) & (NN-1)];
    float p = exp2f(gamma * log2f(wsv));
    wpv[i] = p; l2 += p;
  }
  float wpsum = block_reduce_sum(l2, red);
  float invp = 1.f/wpsum;
  #pragma unroll
  for (int i = 0; i < 8; ++i)
    ws[OFF_WW + (size_t)b*NN + t + i*1024] = wpv[i]*invp;
}

// ---------------- pass 2: bank·d (chunk) ----------------
__global__ __launch_bounds__(256, 4) void bank_pass2(const float* __restrict__ bank, float* __restrict__ ws, int bbase)
{
  int gb = blockIdx.x;
  int b  = bbase + (gb >> 6);
  int n0 = (gb & 63) << 7;
  int t = threadIdx.x;
  int cg = t & 15, rl = t >> 4;
  __shared__ float dS[64];
  if (t < 64) dS[t] = ws[OFF_D + b*64 + t];
  __syncthreads();
  float4 d4 = *(float4*)&dS[cg*4];

  float4 v[8];
  #pragma unroll
  for (int it = 0; it < 8; ++it) {
    int n = n0 + rl + it*16;
    v[it] = *(const float4*)&bank[((size_t)b*NN + n)*MM + cg*4];
  }
  float dd[8];
  #pragma unroll
  for (int it = 0; it < 8; ++it)
    dd[it] = v[it].x*d4.x + v[it].y*d4.y + v[it].z*d4.z + v[it].w*d4.w;
  #pragma unroll
  for (int m = 1; m < 16; m <<= 1) {
    #pragma unroll
    for (int it = 0; it < 8; ++it) dd[it] += __shfl_xor(dd[it], m);
  }
  if (cg == 0) {
    size_t base = (size_t)b*NN + n0 + rl;
    #pragma unroll
    for (int it = 0; it < 8; ++it) ws[OFF_DOTD + base + it*16] = dd[it];
  }
}

// ---------------- addr1: read addressing (chunk) ----------------
__global__ __launch_bounds__(1024, 1) void address1(
    const float* __restrict__ wprev, float* __restrict__ ws, int bbase)
{
  int b = bbase + blockIdx.x, t = threadIdx.x;
  __shared__ float buf[NN];
  __shared__ float red[16];

  float wpr[8];
  float lps = 0.f;
  #pragma unroll
  for (int i = 0; i < 8; ++i) {
    wpr[i] = wprev[(size_t)b*NN + t + i*1024];
    lps += wpr[i];
  }
  float psum = block_reduce_sum(lps, red);

  const float* prm = ws + OFF_PR + b*8;
  float beta = prm[0], g = prm[1], s0 = prm[2], s1 = prm[3], s2 = prm[4], gamma = prm[5], knorm = prm[6];
  float dd2 = ws[OFF_BS + b*8 + 2], dkr = ws[OFF_BS + b*8 + 3];

  float lsum = 0.f;
  #pragma unroll
  for (int i = 0; i < 8; ++i) {
    int n = t + i*1024;
    size_t o = (size_t)b*NN + n;
    float wwv = ws[OFF_WW + o];
    float dot  = ws[OFF_DOTR + o] + wwv * dkr;
    float rn2v = fmaxf(ws[OFF_RN2 + o] + 2.f*wwv*ws[OFF_DOTD + o] + wwv*wwv*dd2, 0.f);
    float c = dot / fmaxf(sqrtf(rn2v) * knorm, 1e-8f);
    float e = __expf(beta * (c - 1.f));
    buf[n] = e;
    lsum += e;
  }
  float esum = block_reduce_sum(lsum, red);
  float ie = g/esum, ip = (1.f-g)/psum;
  #pragma unroll
  for (int i = 0; i < 8; ++i) {
    int n = t + i*1024;
    buf[n] = buf[n]*ie + wpr[i]*ip;
  }
  __syncthreads();
  float l2 = 0.f, lswr = 0.f;
  float wpv[8];
  #pragma unroll
  for (int i = 0; i < 8; ++i) {
    int n = t + i*1024;
    float wsv = s0*buf[(n + NN - 1) & (NN-1)] + s1*buf[n] + s2*buf[(n + 1) & (NN-1)];
    float p = exp2f(gamma * log2f(wsv));
    wpv[i] = p; l2 += p;
    lswr += p * ws[OFF_WW + (size_t)b*NN + n];
  }
  float wpsum = block_reduce_sum(l2, red);
  float invp = 1.f/wpsum;
  #pragma unroll
  for (int i = 0; i < 8; ++i)
    ws[OFF_WR + (size_t)b*NN + t + i*1024] = wpv[i]*invp;
  float swr = block_reduce_sum(lswr, red) * invp;
  if (t == 0) ws[OFF_BS + b*8 + 4] = swr;
}

// ---------------- pass 3: out partials (chunk) ----------------
__global__ __launch_bounds__(256, 4) void bank_pass3(const float* __restrict__ bank, float* __restrict__ ws, int bbase)
{
  int gb = blockIdx.x;
  int b  = bbase + (gb >> 6);
  int ch = gb & 63;
  int n0 = ch << 7;
  int t = threadIdx.x;
  int cg = t & 15, rl = t >> 4;
  __shared__ float osum[64];
  if (t < 64) osum[t] = 0.f;
  __syncthreads();

  float wrv[8];
  #pragma unroll
  for (int it = 0; it < 8; ++it)
    wrv[it] = ws[OFF_WR + (size_t)b*NN + n0 + rl + it*16];
  float4 v[8];
  #pragma unroll
  for (int it = 0; it < 8; ++it) {
    int n = n0 + rl + it*16;
    v[it] = *(const float4*)&bank[((size_t)b*NN + n)*MM + cg*4];
  }
  float a0=0.f, a1=0.f, a2=0.f, a3=0.f;
  #pragma unroll
  for (int it = 0; it < 8; ++it) {
    a0 += wrv[it]*v[it].x; a1 += wrv[it]*v[it].y;
    a2 += wrv[it]*v[it].z; a3 += wrv[it]*v[it].w;
  }
  atomicAdd(&osum[cg*4+0], a0);
  atomicAdd(&osum[cg*4+1], a1);
  atomicAdd(&osum[cg*4+2], a2);
  atomicAdd(&osum[cg*4+3], a3);
  __syncthreads();
  if (t < 64) ws[OFF_POUT + (size_t)(b*CHUNKS + ch)*64 + t] = osum[t];
}

// ---------------- final head (all batches) ----------------
__global__ __launch_bounds__(512) void final_kernel(
    const float* __restrict__ Wsp, const float* __restrict__ bsp,
    const float* __restrict__ Wo,  const float* __restrict__ bo,
    float* __restrict__ out, float* __restrict__ ws)
{
  int b = blockIdx.x, t = threadIdx.x;
  __shared__ float o[64], seq[512];
  if (t < 64) {
    float s = 0.f;
    for (int ch = 0; ch < CHUNKS; ++ch) s += ws[OFF_POUT + ((size_t)b*CHUNKS + ch)*64 + t];
    float swr = ws[OFF_BS + b*8 + 4];
    o[t] = s + swr * ws[OFF_D + b*64 + t];
  }
  __syncthreads();
  float acc = bsp[t];
  for (int i = 0; i < 64; ++i) acc += o[i] * Wsp[i*HIDC + t];
  seq[t] = lrelu(acc);
  __syncthreads();
  if (t < SEQW) {
    float a = bo[t];
    for (int i = 0; i < 512; ++i) a += seq[i] * Wo[i*SEQW + t];
    out[b*SEQW + t] = sigm(a);
  }
}

extern "C" void kernel_launch(void* const* d_in, const int* in_sizes, int n_in,
                              void* d_out, int out_size, void* d_ws, size_t ws_size,
                              hipStream_t stream) {
  const float* x    = (const float*)d_in[0];
  const float* bank = (const float*)d_in[1];
  const float* wrp  = (const float*)d_in[2];
  const float* wwp  = (const float*)d_in[3];
  const float* W0   = (const float*)d_in[4];
  const float* b0   = (const float*)d_in[5];
  const float* W1   = (const float*)d_in[6];
  const float* b1   = (const float*)d_in[7];
  const float* Wc   = (const float*)d_in[8];
  const float* bc   = (const float*)d_in[9];
  const float* Wr   = (const float*)d_in[10];
  const float* br   = (const float*)d_in[11];
  const float* Ww   = (const float*)d_in[12];
  const float* bw   = (const float*)d_in[13];
  const float* Wea  = (const float*)d_in[14];
  const float* bea  = (const float*)d_in[15];
  const float* Wsp  = (const float*)d_in[16];
  const float* bsp  = (const float*)d_in[17];
  const float* Wo   = (const float*)d_in[18];
  const float* bo   = (const float*)d_in[19];
  float* ws  = (float*)d_ws;
  float* out = (float*)d_out;

  ctrl_kernel<<<BB, 512, 0, stream>>>(x, W0,b0, W1,b1, Wc,bc, Wr,br, Ww,bw, ws);
  // batch-chunked pipeline: bank slice (CB*NN*MM*4 = 134 MB) stays L3-resident
  // across p1 -> addr0 -> p2 -> addr1 -> p3 of its chunk.
  for (int c = 0; c < BB; c += CB) {
    bank_pass1<<<CB*CHUNKS, 256, 0, stream>>>(bank, ws, c);
    address0<<<CB, 1024, 0, stream>>>(wwp, Wea, bea, ws, c);
    bank_pass2<<<CB*CHUNKS, 256, 0, stream>>>(bank, ws, c);
    address1<<<CB, 1024, 0, stream>>>(wrp, ws, c);
    bank_pass3<<<CB*CHUNKS, 256, 0, stream>>>(bank, ws, c);
  }
  final_kernel<<<BB, 512, 0, stream>>>(Wsp,bsp, Wo,bo, out, ws);
}

// Round 7
// 248.152 us; speedup vs baseline: 1.3424x; 1.3125x over previous
//
#include <hip/hip_runtime.h>
#include <hip/hip_fp16.h>
#include <math.h>

#define NN 8192
#define MM 64
#define BB 128
#define HIDC 512
#define OUTC 256
#define SEQW 63

#define CHUNKS 64        // pass1: 64 blocks/batch, 128 rows each
#define CH2    32        // pass2/3: 32 blocks/batch, 256 rows each

// ---- workspace layout (float offsets) ----
#define OFF_KR    0
#define OFF_KW    8192
#define OFF_PR    16384
#define OFF_PW    17408
#define OFF_BS    18432                    // per-b 8: [2]=dd2 [3]=dkr [4]=swr
#define OFF_D     19456
#define OFF_PMSUM 27648                    // B*64*64
#define OFF_POUT  551936                   // B*32*64
#define OFF_DOTW  814080                   // B*N each below
#define OFF_DOTR  1862656
#define OFF_RN2   2911232
#define OFF_DOTD  3959808
#define OFF_WW    5008384
#define OFF_WR    6056960
#define OFF_HB    8388608                  // fp16 bank copy: B*N*M halves (134 MB), cast to ushort*

__device__ __forceinline__ float lrelu(float x){ return x > 0.f ? x : 0.01f*x; }
__device__ __forceinline__ float sigm(float x){ return 1.f/(1.f+__expf(-x)); }

__device__ __forceinline__ float2 h2f(unsigned u){
  __half2 h = *reinterpret_cast<__half2*>(&u);
  return __half22float2(h);
}

__device__ float block_reduce_sum(float v, float* red) {
  for (int m = 32; m >= 1; m >>= 1) v += __shfl_xor(v, m);
  int wid = threadIdx.x >> 6;
  int nw = (blockDim.x + 63) >> 6;
  if ((threadIdx.x & 63) == 0) red[wid] = v;
  __syncthreads();
  if (threadIdx.x == 0) { float s = 0.f; for (int i = 0; i < nw; ++i) s += red[i]; red[0] = s; }
  __syncthreads();
  float r = red[0];
  __syncthreads();
  return r;
}

// ---------------- controller MLP ----------------
__global__ __launch_bounds__(512) void ctrl_kernel(
    const float* __restrict__ x,
    const float* __restrict__ W0, const float* __restrict__ b0,
    const float* __restrict__ W1, const float* __restrict__ b1,
    const float* __restrict__ Wc, const float* __restrict__ bc,
    const float* __restrict__ Wr, const float* __restrict__ br,
    const float* __restrict__ Ww, const float* __restrict__ bw,
    float* __restrict__ ws)
{
  int b = blockIdx.x, t = threadIdx.x;
  __shared__ float xs[64];
  __shared__ float h0[512];
  __shared__ float h1[512];
  __shared__ float ct[256];
  __shared__ float rr[70], rw[70];
  if (t < 64) xs[t] = x[b*64 + t];
  __syncthreads();
  float acc = b0[t];
  for (int i = 0; i < 64; ++i) acc += xs[i] * W0[i*HIDC + t];
  h0[t] = lrelu(acc);
  __syncthreads();
  acc = b1[t];
  for (int i = 0; i < 512; ++i) acc += h0[i] * W1[i*HIDC + t];
  h1[t] = lrelu(acc);
  __syncthreads();
  if (t < 256) {
    acc = bc[t];
    for (int i = 0; i < 512; ++i) acc += h1[i] * Wc[i*OUTC + t];
    ct[t] = lrelu(acc);
  }
  __syncthreads();
  if (t < 70) {
    float ar = br[t], aw = bw[t];
    for (int i = 0; i < 256; ++i) { float c = ct[i]; ar += c * Wr[i*70 + t]; aw += c * Ww[i*70 + t]; }
    rr[t] = ar; rw[t] = aw;
  }
  __syncthreads();
  if (t < 64) { ws[OFF_KR + b*64 + t] = rr[t]; ws[OFF_KW + b*64 + t] = rw[t]; }
  if (t == 0) {
    float* p = ws + OFF_PR + b*8;
    p[0] = fmaxf(rr[64], 0.f) + 1e-8f;
    p[1] = sigm(rr[65]);
    float m = fmaxf(rr[66], fmaxf(rr[67], rr[68]));
    float e0 = expf(rr[66]-m), e1 = expf(rr[67]-m), e2 = expf(rr[68]-m);
    float ss = e0+e1+e2;
    p[2] = e0/ss; p[3] = e1/ss; p[4] = e2/ss;
    p[5] = fmaxf(rr[69], 0.f) + 1.f;
    float n2 = 0.f; for (int i = 0; i < 64; ++i) n2 += rr[i]*rr[i];
    p[6] = sqrtf(n2);
  }
  if (t == 1) {
    float* p = ws + OFF_PW + b*8;
    p[0] = fmaxf(rw[64], 0.f) + 1e-8f;
    p[1] = sigm(rw[65]);
    float m = fmaxf(rw[66], fmaxf(rw[67], rw[68]));
    float e0 = expf(rw[66]-m), e1 = expf(rw[67]-m), e2 = expf(rw[68]-m);
    float ss = e0+e1+e2;
    p[2] = e0/ss; p[3] = e1/ss; p[4] = e2/ss;
    p[5] = fmaxf(rw[69], 0.f) + 1.f;
    float n2 = 0.f; for (int i = 0; i < 64; ++i) n2 += rw[i]*rw[i];
    p[6] = sqrtf(n2);
  }
}

// ---------------- pass 1: f32 bank -> dotw/dotr/rn2/msum + fp16 copy ----------------
__global__ __launch_bounds__(256, 4) void bank_pass1(const float* __restrict__ bank,
                                                     float* __restrict__ ws,
                                                     ushort* __restrict__ hbank)
{
  int blk = blockIdx.x;
  int b  = blk >> 6;              // 64 chunks per batch
  int ch = blk & 63;
  int n0 = ch << 7;               // 128 rows per block
  int t = threadIdx.x;
  int cg = t & 15;                // 16 lanes/row, 4 floats each
  int rl = t >> 4;                // 0..15
  __shared__ float kwS[64], krS[64], msum[64];
  if (t < 64) { kwS[t] = ws[OFF_KW + b*64 + t]; krS[t] = ws[OFF_KR + b*64 + t]; msum[t] = 0.f; }
  __syncthreads();
  float4 kw4 = *(float4*)&kwS[cg*4];
  float4 kr4 = *(float4*)&krS[cg*4];

  float4 v[8];
  #pragma unroll
  for (int it = 0; it < 8; ++it) {
    int n = n0 + rl + it*16;
    v[it] = *(const float4*)&bank[((size_t)b*NN + n)*MM + cg*4];
  }
  // fp16 copy write (coalesced: 16 lanes x 8 B = 128 B per row)
  #pragma unroll
  for (int it = 0; it < 8; ++it) {
    int n = n0 + rl + it*16;
    __half2 ha = __floats2half2_rn(v[it].x, v[it].y);
    __half2 hb = __floats2half2_rn(v[it].z, v[it].w);
    uint2 hw;
    hw.x = *reinterpret_cast<unsigned*>(&ha);
    hw.y = *reinterpret_cast<unsigned*>(&hb);
    *(uint2*)&hbank[((size_t)b*NN + n)*MM + cg*4] = hw;
  }
  float dw[8], dr[8], r2[8];
  float m0=0.f, m1=0.f, m2=0.f, m3=0.f;
  #pragma unroll
  for (int it = 0; it < 8; ++it) {
    dw[it] = v[it].x*kw4.x + v[it].y*kw4.y + v[it].z*kw4.z + v[it].w*kw4.w;
    dr[it] = v[it].x*kr4.x + v[it].y*kr4.y + v[it].z*kr4.z + v[it].w*kr4.w;
    r2[it] = v[it].x*v[it].x + v[it].y*v[it].y + v[it].z*v[it].z + v[it].w*v[it].w;
    m0 += v[it].x; m1 += v[it].y; m2 += v[it].z; m3 += v[it].w;
  }
  #pragma unroll
  for (int m = 1; m < 16; m <<= 1) {
    #pragma unroll
    for (int it = 0; it < 8; ++it) {
      dw[it] += __shfl_xor(dw[it], m);
      dr[it] += __shfl_xor(dr[it], m);
      r2[it] += __shfl_xor(r2[it], m);
    }
  }
  if (cg == 0) {
    size_t base = (size_t)b*NN + n0 + rl;
    #pragma unroll
    for (int it = 0; it < 8; ++it) {
      ws[OFF_DOTW + base + it*16] = dw[it];
      ws[OFF_DOTR + base + it*16] = dr[it];
      ws[OFF_RN2  + base + it*16] = r2[it];
    }
  }
  atomicAdd(&msum[cg*4+0], m0);
  atomicAdd(&msum[cg*4+1], m1);
  atomicAdd(&msum[cg*4+2], m2);
  atomicAdd(&msum[cg*4+3], m3);
  __syncthreads();
  if (t < 64) ws[OFF_PMSUM + (size_t)(b*CHUNKS + ch)*64 + t] = msum[t];
}

// ---------------- addr0: ea prefix + write addressing ----------------
__global__ __launch_bounds__(1024, 1) void address0(
    const float* __restrict__ wprev,
    const float* __restrict__ Wea, const float* __restrict__ bea,
    float* __restrict__ ws)
{
  int b = blockIdx.x, t = threadIdx.x;
  __shared__ float buf[NN];
  __shared__ float red[16];
  __shared__ float cat[128], eaS[128], dS[64];

  float wpr[8];
  float lps = 0.f;
  #pragma unroll
  for (int i = 0; i < 8; ++i) {
    wpr[i] = wprev[(size_t)b*NN + t + i*1024];
    lps += wpr[i];
  }
  float psum = block_reduce_sum(lps, red);

  if (t < 64) {
    float s = 0.f;
    for (int ch = 0; ch < CHUNKS; ++ch) s += ws[OFF_PMSUM + ((size_t)b*CHUNKS + ch)*64 + t];
    cat[t] = s * (1.0f/NN);
  } else if (t < 128) {
    cat[t] = ws[OFF_KW + b*64 + (t-64)];
  }
  __syncthreads();
  if (t < 128) {
    float acc = bea[t];
    for (int i = 0; i < 128; ++i) acc += cat[i] * Wea[i*128 + t];
    eaS[t] = acc;
  }
  __syncthreads();
  if (t < 64) {
    float dv = eaS[64+t] - sigm(eaS[t]);
    dS[t] = dv;
    ws[OFF_D + b*64 + t] = dv;
  }
  __syncthreads();
  if (t == 0) {
    float dd = 0.f, dk = 0.f;
    for (int i = 0; i < 64; ++i) { float dv = dS[i]; dd += dv*dv; dk += dv * ws[OFF_KR + b*64 + i]; }
    ws[OFF_BS + b*8 + 2] = dd;
    ws[OFF_BS + b*8 + 3] = dk;
  }
  __syncthreads();

  const float* prm = ws + OFF_PW + b*8;
  float beta = prm[0], g = prm[1], s0 = prm[2], s1 = prm[3], s2 = prm[4], gamma = prm[5], knorm = prm[6];

  float lsum = 0.f;
  #pragma unroll
  for (int i = 0; i < 8; ++i) {
    int n = t + i*1024;
    size_t o = (size_t)b*NN + n;
    float c = ws[OFF_DOTW + o] / fmaxf(sqrtf(ws[OFF_RN2 + o]) * knorm, 1e-8f);
    float e = __expf(beta * (c - 1.f));   // exact shift: cos <= 1
    buf[n] = e;
    lsum += e;
  }
  float esum = block_reduce_sum(lsum, red);
  float ie = g/esum, ip = (1.f-g)/psum;
  #pragma unroll
  for (int i = 0; i < 8; ++i) {
    int n = t + i*1024;
    buf[n] = buf[n]*ie + wpr[i]*ip;
  }
  __syncthreads();
  float l2 = 0.f;
  float wpv[8];
  #pragma unroll
  for (int i = 0; i < 8; ++i) {
    int n = t + i*1024;
    float wsv = s0*buf[(n + NN - 1) & (NN-1)] + s1*buf[n] + s2*buf[(n + 1) & (NN-1)];
    float p = exp2f(gamma * log2f(wsv));
    wpv[i] = p; l2 += p;
  }
  float wpsum = block_reduce_sum(l2, red);
  float invp = 1.f/wpsum;
  #pragma unroll
  for (int i = 0; i < 8; ++i)
    ws[OFF_WW + (size_t)b*NN + t + i*1024] = wpv[i]*invp;
}

// ---------------- pass 2: fp16 bank -> dotd ----------------
__global__ __launch_bounds__(256, 4) void bank_pass2h(const ushort* __restrict__ hb, float* __restrict__ ws)
{
  int blk = blockIdx.x;           // BB*CH2
  int b  = blk >> 5;
  int n0 = (blk & 31) << 8;       // 256 rows per block
  int t = threadIdx.x;
  int cg = t & 7;                 // 8 lanes/row, 8 halves each
  int rl = t >> 3;                // 0..31
  __shared__ float dS[64];
  if (t < 64) dS[t] = ws[OFF_D + b*64 + t];
  __syncthreads();
  float d8[8];
  #pragma unroll
  for (int j = 0; j < 8; ++j) d8[j] = dS[cg*8 + j];

  uint4 hv[8];
  #pragma unroll
  for (int it = 0; it < 8; ++it) {
    int n = n0 + rl + it*32;
    hv[it] = *(const uint4*)&hb[((size_t)b*NN + n)*MM + cg*8];
  }
  float dd[8];
  #pragma unroll
  for (int it = 0; it < 8; ++it) {
    float2 f0 = h2f(hv[it].x), f1 = h2f(hv[it].y), f2 = h2f(hv[it].z), f3 = h2f(hv[it].w);
    dd[it] = f0.x*d8[0] + f0.y*d8[1] + f1.x*d8[2] + f1.y*d8[3]
           + f2.x*d8[4] + f2.y*d8[5] + f3.x*d8[6] + f3.y*d8[7];
  }
  #pragma unroll
  for (int m = 1; m < 8; m <<= 1) {
    #pragma unroll
    for (int it = 0; it < 8; ++it) dd[it] += __shfl_xor(dd[it], m);
  }
  if (cg == 0) {
    size_t base = (size_t)b*NN + n0 + rl;
    #pragma unroll
    for (int it = 0; it < 8; ++it) ws[OFF_DOTD + base + it*32] = dd[it];
  }
}

// ---------------- addr1: read addressing ----------------
__global__ __launch_bounds__(1024, 1) void address1(
    const float* __restrict__ wprev, float* __restrict__ ws)
{
  int b = blockIdx.x, t = threadIdx.x;
  __shared__ float buf[NN];
  __shared__ float red[16];

  float wpr[8];
  float lps = 0.f;
  #pragma unroll
  for (int i = 0; i < 8; ++i) {
    wpr[i] = wprev[(size_t)b*NN + t + i*1024];
    lps += wpr[i];
  }
  float psum = block_reduce_sum(lps, red);

  const float* prm = ws + OFF_PR + b*8;
  float beta = prm[0], g = prm[1], s0 = prm[2], s1 = prm[3], s2 = prm[4], gamma = prm[5], knorm = prm[6];
  float dd2 = ws[OFF_BS + b*8 + 2], dkr = ws[OFF_BS + b*8 + 3];

  float lsum = 0.f;
  #pragma unroll
  for (int i = 0; i < 8; ++i) {
    int n = t + i*1024;
    size_t o = (size_t)b*NN + n;
    float wwv = ws[OFF_WW + o];
    float dot  = ws[OFF_DOTR + o] + wwv * dkr;
    float rn2v = fmaxf(ws[OFF_RN2 + o] + 2.f*wwv*ws[OFF_DOTD + o] + wwv*wwv*dd2, 0.f);
    float c = dot / fmaxf(sqrtf(rn2v) * knorm, 1e-8f);
    float e = __expf(beta * (c - 1.f));
    buf[n] = e;
    lsum += e;
  }
  float esum = block_reduce_sum(lsum, red);
  float ie = g/esum, ip = (1.f-g)/psum;
  #pragma unroll
  for (int i = 0; i < 8; ++i) {
    int n = t + i*1024;
    buf[n] = buf[n]*ie + wpr[i]*ip;
  }
  __syncthreads();
  float l2 = 0.f, lswr = 0.f;
  float wpv[8];
  #pragma unroll
  for (int i = 0; i < 8; ++i) {
    int n = t + i*1024;
    float wsv = s0*buf[(n + NN - 1) & (NN-1)] + s1*buf[n] + s2*buf[(n + 1) & (NN-1)];
    float p = exp2f(gamma * log2f(wsv));
    wpv[i] = p; l2 += p;
    lswr += p * ws[OFF_WW + (size_t)b*NN + n];
  }
  float wpsum = block_reduce_sum(l2, red);
  float invp = 1.f/wpsum;
  #pragma unroll
  for (int i = 0; i < 8; ++i)
    ws[OFF_WR + (size_t)b*NN + t + i*1024] = wpv[i]*invp;
  float swr = block_reduce_sum(lswr, red) * invp;
  if (t == 0) ws[OFF_BS + b*8 + 4] = swr;
}

// ---------------- pass 3: fp16 bank -> out partials ----------------
__global__ __launch_bounds__(256, 4) void bank_pass3h(const ushort* __restrict__ hb, float* __restrict__ ws)
{
  int blk = blockIdx.x;           // BB*CH2
  int b  = blk >> 5;
  int ch = blk & 31;
  int n0 = ch << 8;               // 256 rows
  int t = threadIdx.x;
  int cg = t & 7, rl = t >> 3;
  __shared__ float osum[64];
  if (t < 64) osum[t] = 0.f;
  __syncthreads();

  float wrv[8];
  #pragma unroll
  for (int it = 0; it < 8; ++it)
    wrv[it] = ws[OFF_WR + (size_t)b*NN + n0 + rl + it*32];
  uint4 hv[8];
  #pragma unroll
  for (int it = 0; it < 8; ++it) {
    int n = n0 + rl + it*32;
    hv[it] = *(const uint4*)&hb[((size_t)b*NN + n)*MM + cg*8];
  }
  float a[8];
  #pragma unroll
  for (int j = 0; j < 8; ++j) a[j] = 0.f;
  #pragma unroll
  for (int it = 0; it < 8; ++it) {
    float2 f0 = h2f(hv[it].x), f1 = h2f(hv[it].y), f2 = h2f(hv[it].z), f3 = h2f(hv[it].w);
    float w = wrv[it];
    a[0] += w*f0.x; a[1] += w*f0.y; a[2] += w*f1.x; a[3] += w*f1.y;
    a[4] += w*f2.x; a[5] += w*f2.y; a[6] += w*f3.x; a[7] += w*f3.y;
  }
  // reduce over the 8 row-groups within each wave (lanes differ in bits 3..5)
  #pragma unroll
  for (int m = 8; m < 64; m <<= 1) {
    #pragma unroll
    for (int j = 0; j < 8; ++j) a[j] += __shfl_xor(a[j], m);
  }
  if ((t & 56) == 0) {  // one lane per (wave, cg)
    #pragma unroll
    for (int j = 0; j < 8; ++j) atomicAdd(&osum[cg*8 + j], a[j]);
  }
  __syncthreads();
  if (t < 64) ws[OFF_POUT + (size_t)(b*CH2 + ch)*64 + t] = osum[t];
}

// ---------------- final head ----------------
__global__ __launch_bounds__(512) void final_kernel(
    const float* __restrict__ Wsp, const float* __restrict__ bsp,
    const float* __restrict__ Wo,  const float* __restrict__ bo,
    float* __restrict__ out, float* __restrict__ ws)
{
  int b = blockIdx.x, t = threadIdx.x;
  __shared__ float o[64], seq[512];
  if (t < 64) {
    float s = 0.f;
    for (int ch = 0; ch < CH2; ++ch) s += ws[OFF_POUT + ((size_t)b*CH2 + ch)*64 + t];
    float swr = ws[OFF_BS + b*8 + 4];
    o[t] = s + swr * ws[OFF_D + b*64 + t];
  }
  __syncthreads();
  float acc = bsp[t];
  for (int i = 0; i < 64; ++i) acc += o[i] * Wsp[i*HIDC + t];
  seq[t] = lrelu(acc);
  __syncthreads();
  if (t < SEQW) {
    float a = bo[t];
    for (int i = 0; i < 512; ++i) a += seq[i] * Wo[i*SEQW + t];
    out[b*SEQW + t] = sigm(a);
  }
}

extern "C" void kernel_launch(void* const* d_in, const int* in_sizes, int n_in,
                              void* d_out, int out_size, void* d_ws, size_t ws_size,
                              hipStream_t stream) {
  const float* x    = (const float*)d_in[0];
  const float* bank = (const float*)d_in[1];
  const float* wrp  = (const float*)d_in[2];
  const float* wwp  = (const float*)d_in[3];
  const float* W0   = (const float*)d_in[4];
  const float* b0   = (const float*)d_in[5];
  const float* W1   = (const float*)d_in[6];
  const float* b1   = (const float*)d_in[7];
  const float* Wc   = (const float*)d_in[8];
  const float* bc   = (const float*)d_in[9];
  const float* Wr   = (const float*)d_in[10];
  const float* br   = (const float*)d_in[11];
  const float* Ww   = (const float*)d_in[12];
  const float* bw   = (const float*)d_in[13];
  const float* Wea  = (const float*)d_in[14];
  const float* bea  = (const float*)d_in[15];
  const float* Wsp  = (const float*)d_in[16];
  const float* bsp  = (const float*)d_in[17];
  const float* Wo   = (const float*)d_in[18];
  const float* bo   = (const float*)d_in[19];
  float*  ws  = (float*)d_ws;
  ushort* hb  = (ushort*)(ws + OFF_HB);
  float*  out = (float*)d_out;

  ctrl_kernel<<<BB, 512, 0, stream>>>(x, W0,b0, W1,b1, Wc,bc, Wr,br, Ww,bw, ws);
  bank_pass1<<<BB*CHUNKS, 256, 0, stream>>>(bank, ws, hb);
  address0<<<BB, 1024, 0, stream>>>(wwp, Wea, bea, ws);
  bank_pass2h<<<BB*CH2, 256, 0, stream>>>(hb, ws);
  address1<<<BB, 1024, 0, stream>>>(wrp, ws);
  bank_pass3h<<<BB*CH2, 256, 0, stream>>>(hb, ws);
  final_kernel<<<BB, 512, 0, stream>>>(Wsp,bsp, Wo,bo, out, ws);
}

// Round 8
// 212.784 us; speedup vs baseline: 1.5655x; 1.1662x over previous
//
#include <hip/hip_runtime.h>
#include <hip/hip_fp16.h>
#include <math.h>

#define NN 8192
#define MM 64
#define BB 128
#define HIDC 512
#define OUTC 256
#define SEQW 63

#define CHUNKS 64        // pass1: 64 blocks/batch, 128 rows each
#define CH2    32        // pass2/3: 32 blocks/batch, 256 rows each

// ---- workspace layout (float offsets) ----
#define OFF_KR    0
#define OFF_KW    8192
#define OFF_PR    16384
#define OFF_PW    17408
#define OFF_BS    18432                    // per-b 8: [2]=dd2 [3]=dkr [4]=swr
#define OFF_D     19456
#define OFF_PMSUM 27648                    // B*64*64
#define OFF_POUT  551936                   // B*32*64
#define OFF_DOTW  814080                   // B*N each below
#define OFF_DOTR  1862656
#define OFF_RN2   2911232
#define OFF_DOTD  3959808
#define OFF_WW    5008384
#define OFF_WR    6056960
#define OFF_HB    8388608                  // fp16 bank copy: B*N*M halves (134 MB)

__device__ __forceinline__ float lrelu(float x){ return x > 0.f ? x : 0.01f*x; }
__device__ __forceinline__ float sigm(float x){ return 1.f/(1.f+__expf(-x)); }

typedef float fx4 __attribute__((ext_vector_type(4)));
__device__ __forceinline__ float4 ntload4(const float* p){
  fx4 v = __builtin_nontemporal_load((const fx4*)p);
  return make_float4(v.x, v.y, v.z, v.w);
}

__device__ __forceinline__ float2 h2f(unsigned u){
  __half2 h = *reinterpret_cast<__half2*>(&u);
  return __half22float2(h);
}

__device__ float block_reduce_sum(float v, float* red) {
  for (int m = 32; m >= 1; m >>= 1) v += __shfl_xor(v, m);
  int wid = threadIdx.x >> 6;
  int nw = (blockDim.x + 63) >> 6;
  if ((threadIdx.x & 63) == 0) red[wid] = v;
  __syncthreads();
  if (threadIdx.x == 0) { float s = 0.f; for (int i = 0; i < nw; ++i) s += red[i]; red[0] = s; }
  __syncthreads();
  float r = red[0];
  __syncthreads();
  return r;
}

// dual reduction: one barrier round for two sums
__device__ float2 block_reduce_sum2(float2 v, float* red) {
  for (int m = 32; m >= 1; m >>= 1) { v.x += __shfl_xor(v.x, m); v.y += __shfl_xor(v.y, m); }
  int wid = threadIdx.x >> 6;
  int nw = (blockDim.x + 63) >> 6;
  if ((threadIdx.x & 63) == 0) { red[wid] = v.x; red[16 + wid] = v.y; }
  __syncthreads();
  if (threadIdx.x == 0) {
    float sx = 0.f, sy = 0.f;
    for (int i = 0; i < nw; ++i) { sx += red[i]; sy += red[16 + i]; }
    red[0] = sx; red[16] = sy;
  }
  __syncthreads();
  float2 r = make_float2(red[0], red[16]);
  __syncthreads();
  return r;
}

// ---------------- controller MLP ----------------
__global__ __launch_bounds__(512) void ctrl_kernel(
    const float* __restrict__ x,
    const float* __restrict__ W0, const float* __restrict__ b0,
    const float* __restrict__ W1, const float* __restrict__ b1,
    const float* __restrict__ Wc, const float* __restrict__ bc,
    const float* __restrict__ Wr, const float* __restrict__ br,
    const float* __restrict__ Ww, const float* __restrict__ bw,
    float* __restrict__ ws)
{
  int b = blockIdx.x, t = threadIdx.x;
  __shared__ float xs[64];
  __shared__ float h0[512];
  __shared__ float h1[512];
  __shared__ float ct[256];
  __shared__ float rr[70], rw[70];
  if (t < 64) xs[t] = x[b*64 + t];
  __syncthreads();
  float acc = b0[t];
  for (int i = 0; i < 64; ++i) acc += xs[i] * W0[i*HIDC + t];
  h0[t] = lrelu(acc);
  __syncthreads();
  acc = b1[t];
  for (int i = 0; i < 512; ++i) acc += h0[i] * W1[i*HIDC + t];
  h1[t] = lrelu(acc);
  __syncthreads();
  if (t < 256) {
    acc = bc[t];
    for (int i = 0; i < 512; ++i) acc += h1[i] * Wc[i*OUTC + t];
    ct[t] = lrelu(acc);
  }
  __syncthreads();
  if (t < 70) {
    float ar = br[t], aw = bw[t];
    for (int i = 0; i < 256; ++i) { float c = ct[i]; ar += c * Wr[i*70 + t]; aw += c * Ww[i*70 + t]; }
    rr[t] = ar; rw[t] = aw;
  }
  __syncthreads();
  if (t < 64) { ws[OFF_KR + b*64 + t] = rr[t]; ws[OFF_KW + b*64 + t] = rw[t]; }
  if (t == 0) {
    float* p = ws + OFF_PR + b*8;
    p[0] = fmaxf(rr[64], 0.f) + 1e-8f;
    p[1] = sigm(rr[65]);
    float m = fmaxf(rr[66], fmaxf(rr[67], rr[68]));
    float e0 = expf(rr[66]-m), e1 = expf(rr[67]-m), e2 = expf(rr[68]-m);
    float ss = e0+e1+e2;
    p[2] = e0/ss; p[3] = e1/ss; p[4] = e2/ss;
    p[5] = fmaxf(rr[69], 0.f) + 1.f;
    float n2 = 0.f; for (int i = 0; i < 64; ++i) n2 += rr[i]*rr[i];
    p[6] = sqrtf(n2);
  }
  if (t == 1) {
    float* p = ws + OFF_PW + b*8;
    p[0] = fmaxf(rw[64], 0.f) + 1e-8f;
    p[1] = sigm(rw[65]);
    float m = fmaxf(rw[66], fmaxf(rw[67], rw[68]));
    float e0 = expf(rw[66]-m), e1 = expf(rw[67]-m), e2 = expf(rw[68]-m);
    float ss = e0+e1+e2;
    p[2] = e0/ss; p[3] = e1/ss; p[4] = e2/ss;
    p[5] = fmaxf(rw[69], 0.f) + 1.f;
    float n2 = 0.f; for (int i = 0; i < 64; ++i) n2 += rw[i]*rw[i];
    p[6] = sqrtf(n2);
  }
}

// ---------------- pass 1: f32 bank (nt) -> dotw/dotr/rn2/msum + fp16 copy ----------------
__global__ __launch_bounds__(256, 4) void bank_pass1(const float* __restrict__ bank,
                                                     float* __restrict__ ws,
                                                     ushort* __restrict__ hbank)
{
  int blk = blockIdx.x;
  int b  = blk >> 6;              // 64 chunks per batch
  int ch = blk & 63;
  int n0 = ch << 7;               // 128 rows per block
  int t = threadIdx.x;
  int cg = t & 15;                // 16 lanes/row, 4 floats each
  int rl = t >> 4;                // 0..15
  __shared__ float kwS[64], krS[64], msum[64];
  if (t < 64) { kwS[t] = ws[OFF_KW + b*64 + t]; krS[t] = ws[OFF_KR + b*64 + t]; msum[t] = 0.f; }
  __syncthreads();
  float4 kw4 = *(float4*)&kwS[cg*4];
  float4 kr4 = *(float4*)&krS[cg*4];

  float4 v[8];
  #pragma unroll
  for (int it = 0; it < 8; ++it) {
    int n = n0 + rl + it*16;
    v[it] = ntload4(&bank[((size_t)b*NN + n)*MM + cg*4]);   // nt: never re-read, keep out of L3
  }
  // fp16 copy write (temporal: we WANT this resident in L3 for p2/p3)
  #pragma unroll
  for (int it = 0; it < 8; ++it) {
    int n = n0 + rl + it*16;
    __half2 ha = __floats2half2_rn(v[it].x, v[it].y);
    __half2 hb = __floats2half2_rn(v[it].z, v[it].w);
    uint2 hw;
    hw.x = *reinterpret_cast<unsigned*>(&ha);
    hw.y = *reinterpret_cast<unsigned*>(&hb);
    *(uint2*)&hbank[((size_t)b*NN + n)*MM + cg*4] = hw;
  }
  float dw[8], dr[8], r2[8];
  float m0=0.f, m1=0.f, m2=0.f, m3=0.f;
  #pragma unroll
  for (int it = 0; it < 8; ++it) {
    dw[it] = v[it].x*kw4.x + v[it].y*kw4.y + v[it].z*kw4.z + v[it].w*kw4.w;
    dr[it] = v[it].x*kr4.x + v[it].y*kr4.y + v[it].z*kr4.z + v[it].w*kr4.w;
    r2[it] = v[it].x*v[it].x + v[it].y*v[it].y + v[it].z*v[it].z + v[it].w*v[it].w;
    m0 += v[it].x; m1 += v[it].y; m2 += v[it].z; m3 += v[it].w;
  }
  #pragma unroll
  for (int m = 1; m < 16; m <<= 1) {
    #pragma unroll
    for (int it = 0; it < 8; ++it) {
      dw[it] += __shfl_xor(dw[it], m);
      dr[it] += __shfl_xor(dr[it], m);
      r2[it] += __shfl_xor(r2[it], m);
    }
  }
  if (cg == 0) {
    size_t base = (size_t)b*NN + n0 + rl;
    #pragma unroll
    for (int it = 0; it < 8; ++it) {
      ws[OFF_DOTW + base + it*16] = dw[it];
      ws[OFF_DOTR + base + it*16] = dr[it];
      ws[OFF_RN2  + base + it*16] = r2[it];
    }
  }
  atomicAdd(&msum[cg*4+0], m0);
  atomicAdd(&msum[cg*4+1], m1);
  atomicAdd(&msum[cg*4+2], m2);
  atomicAdd(&msum[cg*4+3], m3);
  __syncthreads();
  if (t < 64) ws[OFF_PMSUM + (size_t)(b*CHUNKS + ch)*64 + t] = msum[t];
}

// ---------------- addr0: ea prefix + write addressing ----------------
__global__ __launch_bounds__(1024, 1) void address0(
    const float* __restrict__ wprev,
    const float* __restrict__ Wea, const float* __restrict__ bea,
    float* __restrict__ ws)
{
  int b = blockIdx.x, t = threadIdx.x;
  __shared__ float buf[NN];
  __shared__ float red[32];
  __shared__ float cat[128], eaS[128], dS[64];

  float wpr[8];
  float lps = 0.f;
  #pragma unroll
  for (int i = 0; i < 8; ++i) {
    wpr[i] = wprev[(size_t)b*NN + t + i*1024];
    lps += wpr[i];
  }

  // ea prefix
  if (t < 64) {
    float s = 0.f;
    for (int ch = 0; ch < CHUNKS; ++ch) s += ws[OFF_PMSUM + ((size_t)b*CHUNKS + ch)*64 + t];
    cat[t] = s * (1.0f/NN);
  } else if (t < 128) {
    cat[t] = ws[OFF_KW + b*64 + (t-64)];
  }
  __syncthreads();
  if (t < 128) {
    float acc = bea[t];
    for (int i = 0; i < 128; ++i) acc += cat[i] * Wea[i*128 + t];
    eaS[t] = acc;
  }
  __syncthreads();
  if (t < 64) {
    float dv = eaS[64+t] - sigm(eaS[t]);
    dS[t] = dv;
    ws[OFF_D + b*64 + t] = dv;
  }
  __syncthreads();
  if (t == 0) {
    float dd = 0.f, dk = 0.f;
    for (int i = 0; i < 64; ++i) { float dv = dS[i]; dd += dv*dv; dk += dv * ws[OFF_KR + b*64 + i]; }
    ws[OFF_BS + b*8 + 2] = dd;
    ws[OFF_BS + b*8 + 3] = dk;
  }

  const float* prm = ws + OFF_PW + b*8;
  float beta = prm[0], g = prm[1], s0 = prm[2], s1 = prm[3], s2 = prm[4], gamma = prm[5], knorm = prm[6];

  float lsum = 0.f;
  #pragma unroll
  for (int i = 0; i < 8; ++i) {
    int n = t + i*1024;
    size_t o = (size_t)b*NN + n;
    float c = ws[OFF_DOTW + o] / fmaxf(sqrtf(ws[OFF_RN2 + o]) * knorm, 1e-8f);
    float e = __expf(beta * (c - 1.f));   // exact shift: cos <= 1
    buf[n] = e;
    lsum += e;
  }
  float2 se = block_reduce_sum2(make_float2(lps, lsum), red);  // psum, esum in one round
  float ie = g/se.y, ip = (1.f-g)/se.x;
  #pragma unroll
  for (int i = 0; i < 8; ++i) {
    int n = t + i*1024;
    buf[n] = buf[n]*ie + wpr[i]*ip;
  }
  __syncthreads();
  float l2 = 0.f;
  float wpv[8];
  #pragma unroll
  for (int i = 0; i < 8; ++i) {
    int n = t + i*1024;
    float wsv = s0*buf[(n + NN - 1) & (NN-1)] + s1*buf[n] + s2*buf[(n + 1) & (NN-1)];
    float p = exp2f(gamma * log2f(wsv));
    wpv[i] = p; l2 += p;
  }
  float wpsum = block_reduce_sum(l2, red);
  float invp = 1.f/wpsum;
  #pragma unroll
  for (int i = 0; i < 8; ++i)
    ws[OFF_WW + (size_t)b*NN + t + i*1024] = wpv[i]*invp;
}

// ---------------- pass 2: fp16 bank -> dotd (REVERSE batch order: read hottest L3 lines first) ----------------
__global__ __launch_bounds__(256, 4) void bank_pass2h(const ushort* __restrict__ hb, float* __restrict__ ws)
{
  int blk = blockIdx.x;           // BB*CH2
  int b  = (BB - 1) - (blk >> 5); // reversed: most recently written fp16 first
  int n0 = (blk & 31) << 8;       // 256 rows per block
  int t = threadIdx.x;
  int cg = t & 7;                 // 8 lanes/row, 8 halves each
  int rl = t >> 3;                // 0..31
  __shared__ float dS[64];
  if (t < 64) dS[t] = ws[OFF_D + b*64 + t];
  __syncthreads();
  float d8[8];
  #pragma unroll
  for (int j = 0; j < 8; ++j) d8[j] = dS[cg*8 + j];

  uint4 hv[8];
  #pragma unroll
  for (int it = 0; it < 8; ++it) {
    int n = n0 + rl + it*32;
    hv[it] = *(const uint4*)&hb[((size_t)b*NN + n)*MM + cg*8];
  }
  float dd[8];
  #pragma unroll
  for (int it = 0; it < 8; ++it) {
    float2 f0 = h2f(hv[it].x), f1 = h2f(hv[it].y), f2 = h2f(hv[it].z), f3 = h2f(hv[it].w);
    dd[it] = f0.x*d8[0] + f0.y*d8[1] + f1.x*d8[2] + f1.y*d8[3]
           + f2.x*d8[4] + f2.y*d8[5] + f3.x*d8[6] + f3.y*d8[7];
  }
  #pragma unroll
  for (int m = 1; m < 8; m <<= 1) {
    #pragma unroll
    for (int it = 0; it < 8; ++it) dd[it] += __shfl_xor(dd[it], m);
  }
  if (cg == 0) {
    size_t base = (size_t)b*NN + n0 + rl;
    #pragma unroll
    for (int it = 0; it < 8; ++it) ws[OFF_DOTD + base + it*32] = dd[it];
  }
}

// ---------------- addr1: read addressing ----------------
__global__ __launch_bounds__(1024, 1) void address1(
    const float* __restrict__ wprev, float* __restrict__ ws)
{
  int b = blockIdx.x, t = threadIdx.x;
  __shared__ float buf[NN];
  __shared__ float red[32];

  float wpr[8];
  float lps = 0.f;
  #pragma unroll
  for (int i = 0; i < 8; ++i) {
    wpr[i] = wprev[(size_t)b*NN + t + i*1024];
    lps += wpr[i];
  }

  const float* prm = ws + OFF_PR + b*8;
  float beta = prm[0], g = prm[1], s0 = prm[2], s1 = prm[3], s2 = prm[4], gamma = prm[5], knorm = prm[6];
  float dd2 = ws[OFF_BS + b*8 + 2], dkr = ws[OFF_BS + b*8 + 3];

  float lsum = 0.f;
  #pragma unroll
  for (int i = 0; i < 8; ++i) {
    int n = t + i*1024;
    size_t o = (size_t)b*NN + n;
    float wwv = ws[OFF_WW + o];
    float dot  = ws[OFF_DOTR + o] + wwv * dkr;
    float rn2v = fmaxf(ws[OFF_RN2 + o] + 2.f*wwv*ws[OFF_DOTD + o] + wwv*wwv*dd2, 0.f);
    float c = dot / fmaxf(sqrtf(rn2v) * knorm, 1e-8f);
    float e = __expf(beta * (c - 1.f));
    buf[n] = e;
    lsum += e;
  }
  float2 se = block_reduce_sum2(make_float2(lps, lsum), red);  // psum, esum
  float ie = g/se.y, ip = (1.f-g)/se.x;
  #pragma unroll
  for (int i = 0; i < 8; ++i) {
    int n = t + i*1024;
    buf[n] = buf[n]*ie + wpr[i]*ip;
  }
  __syncthreads();
  float l2 = 0.f, lswr = 0.f;
  float wpv[8];
  #pragma unroll
  for (int i = 0; i < 8; ++i) {
    int n = t + i*1024;
    float wsv = s0*buf[(n + NN - 1) & (NN-1)] + s1*buf[n] + s2*buf[(n + 1) & (NN-1)];
    float p = exp2f(gamma * log2f(wsv));
    wpv[i] = p; l2 += p;
    lswr += p * ws[OFF_WW + (size_t)b*NN + n];
  }
  float2 ps = block_reduce_sum2(make_float2(l2, lswr), red);   // wpsum, swr-raw
  float invp = 1.f/ps.x;
  #pragma unroll
  for (int i = 0; i < 8; ++i)
    ws[OFF_WR + (size_t)b*NN + t + i*1024] = wpv[i]*invp;
  if (t == 0) ws[OFF_BS + b*8 + 4] = ps.y * invp;
}

// ---------------- pass 3: fp16 bank -> out partials (normal order) ----------------
__global__ __launch_bounds__(256, 4) void bank_pass3h(const ushort* __restrict__ hb, float* __restrict__ ws)
{
  int blk = blockIdx.x;           // BB*CH2
  int b  = blk >> 5;
  int ch = blk & 31;
  int n0 = ch << 8;               // 256 rows
  int t = threadIdx.x;
  int cg = t & 7, rl = t >> 3;
  __shared__ float osum[64];
  if (t < 64) osum[t] = 0.f;
  __syncthreads();

  float wrv[8];
  #pragma unroll
  for (int it = 0; it < 8; ++it)
    wrv[it] = ws[OFF_WR + (size_t)b*NN + n0 + rl + it*32];
  uint4 hv[8];
  #pragma unroll
  for (int it = 0; it < 8; ++it) {
    int n = n0 + rl + it*32;
    hv[it] = *(const uint4*)&hb[((size_t)b*NN + n)*MM + cg*8];
  }
  float a[8];
  #pragma unroll
  for (int j = 0; j < 8; ++j) a[j] = 0.f;
  #pragma unroll
  for (int it = 0; it < 8; ++it) {
    float2 f0 = h2f(hv[it].x), f1 = h2f(hv[it].y), f2 = h2f(hv[it].z), f3 = h2f(hv[it].w);
    float w = wrv[it];
    a[0] += w*f0.x; a[1] += w*f0.y; a[2] += w*f1.x; a[3] += w*f1.y;
    a[4] += w*f2.x; a[5] += w*f2.y; a[6] += w*f3.x; a[7] += w*f3.y;
  }
  #pragma unroll
  for (int m = 8; m < 64; m <<= 1) {
    #pragma unroll
    for (int j = 0; j < 8; ++j) a[j] += __shfl_xor(a[j], m);
  }
  if ((t & 56) == 0) {
    #pragma unroll
    for (int j = 0; j < 8; ++j) atomicAdd(&osum[cg*8 + j], a[j]);
  }
  __syncthreads();
  if (t < 64) ws[OFF_POUT + (size_t)(b*CH2 + ch)*64 + t] = osum[t];
}

// ---------------- final head ----------------
__global__ __launch_bounds__(512) void final_kernel(
    const float* __restrict__ Wsp, const float* __restrict__ bsp,
    const float* __restrict__ Wo,  const float* __restrict__ bo,
    float* __restrict__ out, float* __restrict__ ws)
{
  int b = blockIdx.x, t = threadIdx.x;
  __shared__ float o[64], seq[512];
  if (t < 64) {
    float s = 0.f;
    for (int ch = 0; ch < CH2; ++ch) s += ws[OFF_POUT + ((size_t)b*CH2 + ch)*64 + t];
    float swr = ws[OFF_BS + b*8 + 4];
    o[t] = s + swr * ws[OFF_D + b*64 + t];
  }
  __syncthreads();
  float acc = bsp[t];
  for (int i = 0; i < 64; ++i) acc += o[i] * Wsp[i*HIDC + t];
  seq[t] = lrelu(acc);
  __syncthreads();
  if (t < SEQW) {
    float a = bo[t];
    for (int i = 0; i < 512; ++i) a += seq[i] * Wo[i*SEQW + t];
    out[b*SEQW + t] = sigm(a);
  }
}

extern "C" void kernel_launch(void* const* d_in, const int* in_sizes, int n_in,
                              void* d_out, int out_size, void* d_ws, size_t ws_size,
                              hipStream_t stream) {
  const float* x    = (const float*)d_in[0];
  const float* bank = (const float*)d_in[1];
  const float* wrp  = (const float*)d_in[2];
  const float* wwp  = (const float*)d_in[3];
  const float* W0   = (const float*)d_in[4];
  const float* b0   = (const float*)d_in[5];
  const float* W1   = (const float*)d_in[6];
  const float* b1   = (const float*)d_in[7];
  const float* Wc   = (const float*)d_in[8];
  const float* bc   = (const float*)d_in[9];
  const float* Wr   = (const float*)d_in[10];
  const float* br   = (const float*)d_in[11];
  const float* Ww   = (const float*)d_in[12];
  const float* bw   = (const float*)d_in[13];
  const float* Wea  = (const float*)d_in[14];
  const float* bea  = (const float*)d_in[15];
  const float* Wsp  = (const float*)d_in[16];
  const float* bsp  = (const float*)d_in[17];
  const float* Wo   = (const float*)d_in[18];
  const float* bo   = (const float*)d_in[19];
  float*  ws  = (float*)d_ws;
  ushort* hb  = (ushort*)(ws + OFF_HB);
  float*  out = (float*)d_out;

  ctrl_kernel<<<BB, 512, 0, stream>>>(x, W0,b0, W1,b1, Wc,bc, Wr,br, Ww,bw, ws);
  bank_pass1<<<BB*CHUNKS, 256, 0, stream>>>(bank, ws, hb);
  address0<<<BB, 1024, 0, stream>>>(wwp, Wea, bea, ws);
  bank_pass2h<<<BB*CH2, 256, 0, stream>>>(hb, ws);
  address1<<<BB, 1024, 0, stream>>>(wrp, ws);
  bank_pass3h<<<BB*CH2, 256, 0, stream>>>(hb, ws);
  final_kernel<<<BB, 512, 0, stream>>>(Wsp,bsp, Wo,bo, out, ws);
}